// Round 1
// baseline (11933.566 us; speedup 1.0000x reference)
//
#include <hip/hip_runtime.h>
#include <math.h>

// ---------- helpers ----------
__device__ __forceinline__ float wsum(float v){
  #pragma unroll
  for (int o=32;o;o>>=1) v += __shfl_xor(v,o);
  return v;
}
__device__ __forceinline__ float wmaxr(float v){
  #pragma unroll
  for (int o=32;o;o>>=1) v = fmaxf(v,__shfl_xor(v,o));
  return v;
}
__device__ __forceinline__ float geluf(float x){
  return 0.5f*x*(1.0f+erff(x*0.7071067811865475f));
}
// order-preserving float->uint key for atomicMax
__device__ __forceinline__ unsigned fkey(float f){
  unsigned b=__float_as_uint(f);
  return (b&0x80000000u)? ~b : (b|0x80000000u);
}
__device__ __forceinline__ float fdec(unsigned k){
  unsigned b=(k&0x80000000u)? (k&0x7fffffffu) : ~k;
  return __uint_as_float(b);
}

// ---------- mask dtype detection (bool uploaded as int32 vs bytes) ----------
__global__ void detect_mask_kernel(const int* __restrict__ m, long long n, int* flag){
  long long i = (long long)blockIdx.x*256 + threadIdx.x;
  bool bad = (i<n) && (m[i]!=0 && m[i]!=1);
  if (__any(bad)) { if ((threadIdx.x&63)==0) atomicOr(flag,1); }
}

// ---------- generic tiled f32 GEMM ----------
// out[z] = act( A[z] @ W[z] + bias ) + res[z]
// transW=0: W is K x N (ldw);  transW=1: W is N x K (ldw) i.e. access W[n*ldw+k]
#define BM 64
#define BN 64
#define BKT 16
__global__ __launch_bounds__(256)
void gemm_f32(const float* __restrict__ A, int lda, long long sA,
              const float* __restrict__ W, int ldw, long long sW, int transW,
              const float* __restrict__ bias,
              const float* __restrict__ res, int ldr, long long sR,
              float* __restrict__ out, int ldo, long long sO,
              int M, int N, int K, int act)
{
  __shared__ float As[BKT][BM+1];
  __shared__ float Ws[BKT][BN+1];
  int z = blockIdx.z;
  A += (long long)z*sA; W += (long long)z*sW; out += (long long)z*sO;
  if (res) res += (long long)z*sR;
  int tid = threadIdx.x;
  int tx = tid & 15, ty = tid >> 4;
  int rowBase = blockIdx.y*BM;
  int colBase = blockIdx.x*BN;
  float acc[4][4] = {};
  for (int k0=0;k0<K;k0+=BKT){
    for (int i=tid;i<BM*BKT;i+=256){
      int r = i>>4, kk = i&15;
      int gr = rowBase+r, gk = k0+kk;
      As[kk][r] = (gr<M && gk<K) ? A[(long long)gr*lda + gk] : 0.f;
    }
    if (!transW){
      for (int i=tid;i<BKT*BN;i+=256){
        int kk = i>>6, c = i&63;
        int gc = colBase+c, gk = k0+kk;
        Ws[kk][c] = (gc<N && gk<K) ? W[(long long)gk*ldw + gc] : 0.f;
      }
    } else {
      for (int i=tid;i<BKT*BN;i+=256){
        int c = i>>4, kk = i&15;
        int gc = colBase+c, gk = k0+kk;
        Ws[kk][c] = (gc<N && gk<K) ? W[(long long)gc*ldw + gk] : 0.f;
      }
    }
    __syncthreads();
    #pragma unroll
    for (int kk=0;kk<BKT;kk++){
      float a[4], b[4];
      #pragma unroll
      for (int m=0;m<4;m++) a[m]=As[kk][ty*4+m];
      #pragma unroll
      for (int n=0;n<4;n++) b[n]=Ws[kk][tx*4+n];
      #pragma unroll
      for (int m=0;m<4;m++)
        #pragma unroll
        for (int n=0;n<4;n++)
          acc[m][n] += a[m]*b[n];
    }
    __syncthreads();
  }
  #pragma unroll
  for (int m=0;m<4;m++){
    int gr = rowBase + ty*4 + m;
    if (gr>=M) continue;
    #pragma unroll
    for (int n=0;n<4;n++){
      int gc = colBase + tx*4 + n;
      if (gc>=N) continue;
      float v = acc[m][n];
      if (bias) v += bias[gc];
      if (act==1) v = geluf(v);
      else if (act==2) v = v*(1.f/(1.f+__expf(-1.702f*v)));
      if (res) v += res[(long long)gr*ldr + gc];
      out[(long long)gr*ldo + gc] = v;
    }
  }
}

// ---------- row softmax with optional mask ----------
__global__ __launch_bounds__(256)
void softmax_kernel(float* __restrict__ S, int ld, long long sS, int cols, float alpha,
                    const void* __restrict__ mask, long long maskoff, int maskld,
                    const int* __restrict__ modeflag)
{
  __shared__ float buf[2064];
  __shared__ float red[4];
  int row = blockIdx.x, z = blockIdx.y;
  float* p = S + (long long)z*sS + (long long)row*ld;
  int tid = threadIdx.x;
  int mode = 0;
  if (mask && modeflag) mode = *modeflag;
  float mx = -3.4e38f;
  for (int c=tid;c<cols;c+=256){
    float v = p[c]*alpha;
    if (mask){
      long long mi = maskoff + (long long)row*maskld + c;
      bool ok = mode ? (((const unsigned char*)mask)[mi]!=0)
                     : (((const int*)mask)[mi]!=0);
      if (!ok) v = -3.4e38f;
    }
    buf[c] = v;
    mx = fmaxf(mx, v);
  }
  mx = wmaxr(mx);
  int wid = tid>>6, lane = tid&63;
  if (lane==0) red[wid]=mx;
  __syncthreads();
  mx = fmaxf(fmaxf(red[0],red[1]),fmaxf(red[2],red[3]));
  __syncthreads();
  float sum=0.f;
  for (int c=tid;c<cols;c+=256){
    float v = buf[c];
    float e = (v > -1.0e37f) ? __expf(v-mx) : 0.f;
    buf[c]=e; sum += e;
  }
  sum = wsum(sum);
  if (lane==0) red[wid]=sum;
  __syncthreads();
  sum = red[0]+red[1]+red[2]+red[3];
  float inv = 1.f/sum;
  for (int c=tid;c<cols;c+=256) p[c] = buf[c]*inv;
}

// ---------- LayerNorm, C=384, 128 threads ----------
__global__ __launch_bounds__(128)
void ln_kernel(const float* __restrict__ in, const float* __restrict__ g,
               const float* __restrict__ bt, float* __restrict__ out)
{
  long long row = blockIdx.x;
  const float* p = in + row*384;
  int tid = threadIdx.x;
  float v0=p[tid], v1=p[tid+128], v2=p[tid+256];
  float s = v0+v1+v2;
  float ss = v0*v0+v1*v1+v2*v2;
  __shared__ float r1[2], r2[2];
  s = wsum(s); ss = wsum(ss);
  int wid=tid>>6, lane=tid&63;
  if (lane==0){ r1[wid]=s; r2[wid]=ss; }
  __syncthreads();
  float mean=(r1[0]+r1[1])*(1.f/384.f);
  float var =(r2[0]+r2[1])*(1.f/384.f)-mean*mean;
  float rstd=rsqrtf(var+1e-5f);
  float* o = out + row*384;
  o[tid]     = (v0-mean)*rstd*g[tid]+bt[tid];
  o[tid+128] = (v1-mean)*rstd*g[tid+128]+bt[tid+128];
  o[tid+256] = (v2-mean)*rstd*g[tid+256]+bt[tid+256];
}

// ---------- elementwise ----------
__global__ void ew_x2_kernel(float* x1, const float* ffn, const float* ada, long long n){
  long long i=(long long)blockIdx.x*256+threadIdx.x;
  if (i<n) x1[i] = x1[i] + ffn[i] + 0.5f*ada[i];
}
__global__ void copy_pts_kernel(const float* __restrict__ x2, float* __restrict__ pts){
  long long i=(long long)blockIdx.x*256+threadIdx.x;
  if (i < 8192ll*384){
    long long b = i/(2048ll*384);
    long long rem = i%(2048ll*384);
    pts[i] = x2[(b*2049+1)*384 + rem];
  }
}
__global__ void copy_cls_kernel(const float* __restrict__ x2, float* __restrict__ out){
  int i = blockIdx.x*256+threadIdx.x;
  if (i < 4*384){
    int b=i/384, c=i%384;
    out[(long long)b*2049*384 + c] = x2[(long long)b*2049*384 + c];
  }
}

// ---------- segment scatter (sum + max + count) ----------
__global__ __launch_bounds__(128)
void scatter_seg_kernel(const float* __restrict__ feat, const int* __restrict__ seg,
                        float* __restrict__ fsum, unsigned* __restrict__ fmax,
                        float* __restrict__ cnt)
{
  int n = blockIdx.x;
  int s = seg[n];
  const float* p = feat + (long long)n*384;
  int tid = threadIdx.x;
  #pragma unroll
  for (int k=0;k<3;k++){
    int c = tid + k*128;
    float v = p[c];
    atomicAdd(&fsum[(long long)s*384+c], v);
    atomicMax(&fmax[(long long)s*384+c], fkey(v));
  }
  if (tid==0) atomicAdd(&cnt[s], 1.0f);
}

// ---------- cell = bn_gelu(max + mean) ----------
__global__ __launch_bounds__(128)
void cell_kernel(const float* __restrict__ fsum, const unsigned* __restrict__ fmax,
                 const float* __restrict__ cnt,
                 const float* __restrict__ g, const float* __restrict__ bb,
                 const float* __restrict__ m, const float* __restrict__ v,
                 float* __restrict__ out)
{
  int s = blockIdx.x;
  float cn = cnt[s];
  float denom = fmaxf(cn, 1.f);
  int tid = threadIdx.x;
  #pragma unroll
  for (int k=0;k<3;k++){
    int c = tid + k*128;
    float mx = (cn>0.f) ? fdec(fmax[(long long)s*384+c]) : 0.f;
    float t = mx + fsum[(long long)s*384+c]/denom;
    t = (t - m[c])*rsqrtf(v[c]+1e-5f)*g[c] + bb[c];
    out[(long long)s*384+c] = geluf(t);
  }
}

// ---------- final cosine-sim weighted combine ----------
__global__ __launch_bounds__(128)
void combine_kernel(const float* __restrict__ pts, const float* __restrict__ cell3,
                    const int* __restrict__ cluster, const float* __restrict__ cell2,
                    const int* __restrict__ gidx, float* __restrict__ out)
{
  int n = blockIdx.x;
  int tid = threadIdx.x;
  __shared__ float sdot[6], ssq[6], sw[6];
  __shared__ int soff[6];
  __shared__ float red[2][2];
  __shared__ float sn3;
  const float* x3 = cell3 + (long long)cluster[n]*384;
  int wid=tid>>6, lane=tid&63;
  float sq=0.f;
  for (int c=tid;c<384;c+=128){ float v=x3[c]; sq+=v*v; }
  sq = wsum(sq);
  if (lane==0) red[0][wid]=sq;
  __syncthreads();
  if (tid==0) sn3 = sqrtf(red[0][0]+red[0][1]);
  __syncthreads();
  for (int i=0;i<6;i++){
    int gi = gidx[(long long)i*8192 + n];
    if (tid==0) soff[i]=gi;
    const float* r = cell2 + ((long long)i*4096 + gi)*384;
    float d=0.f, s2=0.f;
    for (int c=tid;c<384;c+=128){ float a=r[c]; d+=a*x3[c]; s2+=a*a; }
    d = wsum(d); s2 = wsum(s2);
    if (lane==0){ red[0][wid]=d; red[1][wid]=s2; }
    __syncthreads();
    if (tid==0){ sdot[i]=red[0][0]+red[0][1]; ssq[i]=red[1][0]+red[1][1]; }
    __syncthreads();
  }
  if (tid==0){
    float ssumv=0.f; float sims[6];
    for (int i=0;i<6;i++){
      float nrm = sqrtf(ssq[i])*sn3;
      float s = (sdot[i]/fmaxf(nrm,1e-8f) + 1.f)*0.5f;
      sims[i]=s; ssumv+=s;
    }
    for (int i=0;i<6;i++) sw[i]=sims[i]/ssumv;
  }
  __syncthreads();
  int b = n>>11, gp = n&2047;
  float* o = out + ((long long)(b*2049 + 1 + gp))*384;
  for (int c=tid;c<384;c+=128){
    float acc=0.f;
    #pragma unroll
    for (int i=0;i<6;i++){
      const float* r = cell2 + ((long long)i*4096 + soff[i])*384;
      acc += sw[i]*r[c];
    }
    o[c] = pts[(long long)n*384+c] + 0.5f*acc;
  }
}

// ---------- host ----------
static inline void launch_gemm(hipStream_t s, const float* A,int lda,long long sA,
  const float* W,int ldw,long long sW,int tW, const float* bias,
  const float* res,int ldr,long long sR, float* out,int ldo,long long sO,
  int M,int N,int K,int act,int nb)
{
  dim3 g((N+BN-1)/BN,(M+BM-1)/BM,nb);
  hipLaunchKernelGGL(gemm_f32,g,dim3(256),0,s,
    A,lda,sA,W,ldw,sW,tW,bias,res,ldr,sR,out,ldo,sO,M,N,K,act);
}

extern "C" void kernel_launch(void* const* d_in, const int* in_sizes, int n_in,
                              void* d_out, int out_size, void* d_ws, size_t ws_size,
                              hipStream_t stream)
{
  const float* x       = (const float*)d_in[0];
  const float* norm1_g = (const float*)d_in[2];
  const float* norm1_b = (const float*)d_in[3];
  const float* qkv_w   = (const float*)d_in[4];
  const float* proj_w  = (const float*)d_in[5];
  const float* proj_b  = (const float*)d_in[6];
  const float* norm2_g = (const float*)d_in[7];
  const float* norm2_b = (const float*)d_in[8];
  const float* fc1_w   = (const float*)d_in[9];
  const float* fc1_b   = (const float*)d_in[10];
  const float* fc2_w   = (const float*)d_in[11];
  const float* fc2_b   = (const float*)d_in[12];
  const float* ada1_w  = (const float*)d_in[13];
  const float* ada1_b  = (const float*)d_in[14];
  const float* ada2_w  = (const float*)d_in[15];
  const float* ada2_b  = (const float*)d_in[16];
  const float* bn3_g   = (const float*)d_in[17];
  const float* bn3_b   = (const float*)d_in[18];
  const float* bn3_m   = (const float*)d_in[19];
  const float* bn3_v   = (const float*)d_in[20];
  const float* bn2_g   = (const float*)d_in[21];
  const float* bn2_b   = (const float*)d_in[22];
  const float* bn2_m   = (const float*)d_in[23];
  const float* bn2_v   = (const float*)d_in[24];
  const float* norm3_g = (const float*)d_in[25];
  const float* norm3_b = (const float*)d_in[26];
  const float* a1_qkv_w  = (const float*)d_in[27];
  const float* a1_proj_w = (const float*)d_in[28];
  const float* a1_proj_b = (const float*)d_in[29];
  const void*  maskp     = d_in[30];
  const int*   cluster   = (const int*)d_in[33];
  const int*   fgi       = (const int*)d_in[34];
  float* out = (float*)d_out;

  // workspace layout
  size_t off = 0;
  char* wsb = (char*)d_ws;
  auto alloc = [&](size_t elems)->void*{
    void* p = wsb + off;
    off += ((elems*4)+255) & ~(size_t)255;
    return p;
  };
  float*    bufH  = (float*)alloc(8196ll*384);
  float*    bufQ  = (float*)alloc(8196ll*1152);
  float*    bufO  = (float*)alloc(8196ll*384);
  float*    bufX  = (float*)alloc(8196ll*384);
  float*    bufT  = (float*)alloc(8196ll*1536);  // t1 / fxv; also aliased by inner-attn S
  float*    bufA  = (float*)alloc(8196ll*96);
  float*    ptsb  = (float*)alloc(8192ll*384);
  float*    cnt   = (float*)alloc(1024);
  float*    fsum  = (float*)alloc(1024ll*384);
  unsigned* fmaxe = (unsigned*)alloc(1024ll*384);
  float*    cell3 = (float*)alloc(1024ll*384);
  float*    gc    = (float*)alloc(4096);
  float*    gsum  = (float*)alloc(4096ll*384);
  unsigned* gmaxe = (unsigned*)alloc(4096ll*384);
  float*    cell2 = (float*)alloc(6ll*4096*384);
  float*    Sbuf2 = (float*)alloc(2ll*2048*2048);
  int*      flag  = (int*)alloc(64);
  // inner-attention score buffer aliases [bufT .. cell2 end) — those regions
  // are only written AFTER inner attention completes (sequential stream order).
  float* SbufI = bufT;

  // ---- mask dtype detect ----
  hipMemsetAsync(flag, 0, 4, stream);
  {
    long long nInt = 6ll*2048*2048/4;
    detect_mask_kernel<<<dim3((unsigned)((nInt+255)/256)),dim3(256),0,stream>>>((const int*)maskp, nInt, flag);
  }

  // ---- phase 1: transformer block ----
  ln_kernel<<<8196,128,0,stream>>>(x, norm1_g, norm1_b, bufH);
  launch_gemm(stream, bufH,384,0, qkv_w,1152,0,0, nullptr, nullptr,0,0,
              bufQ,1152,0, 8196,1152,384, 0, 1);
  for (int b=0;b<4;b++){
    const float* qb = bufQ + (long long)b*2049*1152;
    launch_gemm(stream, qb,1152,64, qb+384,1152,64,1, nullptr, nullptr,0,0,
                SbufI,2049,2049ll*2049, 2049,2049,64, 0, 6);
    softmax_kernel<<<dim3(2049,6),256,0,stream>>>(SbufI,2049,2049ll*2049,2049,0.125f,
                                                  nullptr,0,0,nullptr);
    launch_gemm(stream, SbufI,2049,2049ll*2049, qb+768,1152,64,0, nullptr, nullptr,0,0,
                bufO + (long long)b*2049*384,384,64, 2049,64,2049, 0, 6);
  }
  launch_gemm(stream, bufO,384,0, proj_w,384,0,0, proj_b, x,384,0,
              bufX,384,0, 8196,384,384, 0, 1);
  ln_kernel<<<8196,128,0,stream>>>(bufX, norm2_g, norm2_b, bufH);
  launch_gemm(stream, bufH,384,0, fc1_w,1536,0,0, fc1_b, nullptr,0,0,
              bufT,1536,0, 8196,1536,384, 1, 1);
  launch_gemm(stream, bufT,1536,0, fc2_w,384,0,0, fc2_b, nullptr,0,0,
              bufO,384,0, 8196,384,1536, 0, 1);
  launch_gemm(stream, bufO,384,0, ada1_w,96,0,0, ada1_b, nullptr,0,0,
              bufA,96,0, 8196,96,384, 2, 1);
  launch_gemm(stream, bufA,96,0, ada2_w,384,0,0, ada2_b, nullptr,0,0,
              bufH,384,0, 8196,384,96, 0, 1);
  ew_x2_kernel<<<dim3((8196*384+255)/256),256,0,stream>>>(bufX, bufO, bufH, 8196ll*384);
  copy_cls_kernel<<<6,256,0,stream>>>(bufX, out);
  copy_pts_kernel<<<dim3((8192*384+255)/256),256,0,stream>>>(bufX, ptsb);

  // ---- phase 2: cluster pooling -> cell3 ----
  hipMemsetAsync(cnt, 0, 1024*4, stream);
  hipMemsetAsync(fsum, 0, 1024ll*384*4, stream);
  hipMemsetAsync(fmaxe, 0, 1024ll*384*4, stream);
  scatter_seg_kernel<<<8192,128,0,stream>>>(ptsb, cluster, fsum, fmaxe, cnt);
  cell_kernel<<<1024,128,0,stream>>>(fsum, fmaxe, cnt, bn3_g,bn3_b,bn3_m,bn3_v, cell3);

  // ---- phase 3: views ----
  for (int i=0;i<6;i++){
    ln_kernel<<<8192,128,0,stream>>>(ptsb, norm3_g + (long long)i*384, norm3_b + (long long)i*384, bufH);
    launch_gemm(stream, bufH,384,0, a1_qkv_w + (long long)i*384*1152,1152,0,0,
                nullptr, nullptr,0,0, bufQ,1152,0, 8192,1152,384, 0, 1);
    for (int bb=0;bb<2;bb++){
      const float* qb = bufQ + (long long)bb*2*2048*1152;
      launch_gemm(stream, qb,1152,2048ll*1152, qb+384,1152,2048ll*1152,1,
                  nullptr, nullptr,0,0, Sbuf2,2048,2048ll*2048, 2048,2048,384, 0, 2);
      softmax_kernel<<<dim3(2048,2),256,0,stream>>>(Sbuf2,2048,2048ll*2048,2048,
                  0.05103103630798288f, maskp, (long long)i*2048*2048, 2048, flag);
      launch_gemm(stream, Sbuf2,2048,2048ll*2048, qb+768,1152,2048ll*1152,0,
                  nullptr, nullptr,0,0, bufO + (long long)bb*2*2048*384,384,2048ll*384,
                  2048,384,2048, 0, 2);
    }
    launch_gemm(stream, bufO,384,0, a1_proj_w + (long long)i*384*384,384,0,0,
                a1_proj_b + (long long)i*384, ptsb,384,0,
                bufT,384,0, 8192,384,384, 0, 1);
    hipMemsetAsync(gc, 0, 4096*4, stream);
    hipMemsetAsync(gsum, 0, 4096ll*384*4, stream);
    hipMemsetAsync(gmaxe, 0, 4096ll*384*4, stream);
    scatter_seg_kernel<<<8192,128,0,stream>>>(bufT, fgi + (long long)i*8192, gsum, gmaxe, gc);
    cell_kernel<<<4096,128,0,stream>>>(gsum, gmaxe, gc,
        bn2_g + (long long)i*384, bn2_b + (long long)i*384,
        bn2_m + (long long)i*384, bn2_v + (long long)i*384,
        cell2 + (long long)i*4096*384);
  }

  // ---- phase 4: combine ----
  combine_kernel<<<8192,128,0,stream>>>(ptsb, cell3, cluster, cell2, fgi, out);
}

// Round 2
// 2598.247 us; speedup vs baseline: 4.5929x; 4.5929x over previous
//
#include <hip/hip_runtime.h>
#include <math.h>

typedef short bf16x8 __attribute__((ext_vector_type(8)));
typedef float f32x4 __attribute__((ext_vector_type(4)));

// ---------- helpers ----------
__device__ __forceinline__ float wsum(float v){
  #pragma unroll
  for (int o=32;o;o>>=1) v += __shfl_xor(v,o);
  return v;
}
__device__ __forceinline__ float wmaxr(float v){
  #pragma unroll
  for (int o=32;o;o>>=1) v = fmaxf(v,__shfl_xor(v,o));
  return v;
}
__device__ __forceinline__ float geluf(float x){
  return 0.5f*x*(1.0f+erff(x*0.7071067811865475f));
}
__device__ __forceinline__ short fbf(float f){   // fp32 -> bf16 RNE
  unsigned u = __float_as_uint(f);
  unsigned r = (u + 0x7fffu + ((u>>16)&1u)) >> 16;
  return (short)r;
}
__device__ __forceinline__ float bff(short s){
  return __uint_as_float(((unsigned)(unsigned short)s)<<16);
}
__device__ __forceinline__ unsigned fkey(float f){
  unsigned b=__float_as_uint(f);
  return (b&0x80000000u)? ~b : (b|0x80000000u);
}
__device__ __forceinline__ float fdec(unsigned k){
  unsigned b=(k&0x80000000u)? (k&0x7fffffffu) : ~k;
  return __uint_as_float(b);
}

// ---------- mask dtype detection ----------
__global__ void detect_mask_kernel(const int* __restrict__ m, long long n, int* flag){
  long long i = (long long)blockIdx.x*256 + threadIdx.x;
  bool bad = (i<n) && (m[i]!=0 && m[i]!=1);
  if (__any(bad)) { if ((threadIdx.x&63)==0) atomicOr(flag,1); }
}

// ---------- bf16 MFMA GEMM ----------
// out[z] = epilogue( A[z] @ B[z]^T )   A:[M,K] bf16 lda, B:[N,K] bf16 ldb ("B^T layout")
// KS>1: split-K, atomicAdd fp32 into pre-zeroed out (no epilogue).
#define TBM 128
#define TBN 64
#define TBK 32
__global__ __launch_bounds__(256)
void gemm_bf16(const short* __restrict__ A, int lda, long long sA,
               const short* __restrict__ B, int ldb, long long sB,
               const float* __restrict__ bias,
               const float* __restrict__ res, int ldr, long long sR,
               void* __restrict__ out, int ldo, long long sO, int outbf16,
               int M, int N, int K, int act, int KS)
{
  __shared__ short As[TBM*40];
  __shared__ short Bs[TBN*40];
  int zz = blockIdx.z;
  int z = zz / KS, ks = zz - z*KS;
  A += (long long)z*sA; B += (long long)z*sB;
  if (res) res += (long long)z*sR;
  float* outF = (float*)out + (long long)z*sO;
  short* outH = (short*)out + (long long)z*sO;

  int tid = threadIdx.x;
  int rowBase = blockIdx.y*TBM;
  int colBase = blockIdx.x*TBN;

  int Kc = ((K + KS*TBK - 1)/(KS*TBK))*TBK;
  int kbeg = ks*Kc;
  int kend = min(K, kbeg+Kc);
  if (kbeg >= kend) return;

  int w = tid>>6;
  int waveM = w>>1, waveN = w&1;
  int lane = tid&63;
  int lm = lane&15, quad = lane>>4;

  f32x4 acc[4][2] = {};

  for (int k0=kbeg; k0<kend; k0+=TBK){
    #pragma unroll
    for (int p=0;p<2;p++){
      int idx = p*256 + tid;
      int r = idx>>2, kc = (idx&3)*8;
      int gr = rowBase + r, gk = k0 + kc;
      bf16x8 v = {};
      if (gr<M && gk<kend) v = *(const bf16x8*)(A + (long long)gr*lda + gk);
      *(bf16x8*)&As[r*40+kc] = v;
    }
    {
      int n = tid>>2, kc = (tid&3)*8;
      int gn = colBase + n, gk = k0 + kc;
      bf16x8 v = {};
      if (gn<N && gk<kend) v = *(const bf16x8*)(B + (long long)gn*ldb + gk);
      *(bf16x8*)&Bs[n*40+kc] = v;
    }
    __syncthreads();
    bf16x8 af[4], bfr[2];
    #pragma unroll
    for (int tm=0;tm<4;tm++) af[tm] = *(bf16x8*)&As[(waveM*64+tm*16+lm)*40 + quad*8];
    #pragma unroll
    for (int tn=0;tn<2;tn++) bfr[tn] = *(bf16x8*)&Bs[(waveN*32+tn*16+lm)*40 + quad*8];
    #pragma unroll
    for (int tm=0;tm<4;tm++)
      #pragma unroll
      for (int tn=0;tn<2;tn++)
        acc[tm][tn] = __builtin_amdgcn_mfma_f32_16x16x32_bf16(af[tm], bfr[tn], acc[tm][tn], 0,0,0);
    __syncthreads();
  }

  #pragma unroll
  for (int tm=0;tm<4;tm++){
    #pragma unroll
    for (int tn=0;tn<2;tn++){
      int col = colBase + waveN*32 + tn*16 + lm;
      if (col>=N) continue;
      #pragma unroll
      for (int reg=0;reg<4;reg++){
        int row = rowBase + waveM*64 + tm*16 + quad*4 + reg;
        if (row>=M) continue;
        float v = acc[tm][tn][reg];
        if (KS>1){ atomicAdd(&outF[(long long)row*ldo+col], v); continue; }
        if (bias) v += bias[col];
        if (act==1) v = geluf(v);
        else if (act==2) v = v*(1.f/(1.f+__expf(-1.702f*v)));
        if (res) v += res[(long long)row*ldr+col];
        if (outbf16) outH[(long long)row*ldo+col] = fbf(v);
        else         outF[(long long)row*ldo+col] = v;
      }
    }
  }
}

// ---------- fp32 GEMM (small ada path) ----------
#define BM 64
#define BN 64
#define BKT 16
__global__ __launch_bounds__(256)
void gemm_f32(const float* __restrict__ A, int lda, long long sA,
              const float* __restrict__ W, int ldw, long long sW, int transW,
              const float* __restrict__ bias,
              const float* __restrict__ res, int ldr, long long sR,
              float* __restrict__ out, int ldo, long long sO,
              int M, int N, int K, int act)
{
  __shared__ float Asf[BKT][BM+1];
  __shared__ float Wsf[BKT][BN+1];
  int z = blockIdx.z;
  A += (long long)z*sA; W += (long long)z*sW; out += (long long)z*sO;
  if (res) res += (long long)z*sR;
  int tid = threadIdx.x;
  int tx = tid & 15, ty = tid >> 4;
  int rowBase = blockIdx.y*BM;
  int colBase = blockIdx.x*BN;
  float acc[4][4] = {};
  for (int k0=0;k0<K;k0+=BKT){
    for (int i=tid;i<BM*BKT;i+=256){
      int r = i>>4, kk = i&15;
      int gr = rowBase+r, gk = k0+kk;
      Asf[kk][r] = (gr<M && gk<K) ? A[(long long)gr*lda + gk] : 0.f;
    }
    if (!transW){
      for (int i=tid;i<BKT*BN;i+=256){
        int kk = i>>6, c = i&63;
        int gc = colBase+c, gk = k0+kk;
        Wsf[kk][c] = (gc<N && gk<K) ? W[(long long)gk*ldw + gc] : 0.f;
      }
    } else {
      for (int i=tid;i<BKT*BN;i+=256){
        int c = i>>4, kk = i&15;
        int gc = colBase+c, gk = k0+kk;
        Wsf[kk][c] = (gc<N && gk<K) ? W[(long long)gc*ldw + gk] : 0.f;
      }
    }
    __syncthreads();
    #pragma unroll
    for (int kk=0;kk<BKT;kk++){
      float a[4], b[4];
      #pragma unroll
      for (int m=0;m<4;m++) a[m]=Asf[kk][ty*4+m];
      #pragma unroll
      for (int n=0;n<4;n++) b[n]=Wsf[kk][tx*4+n];
      #pragma unroll
      for (int m=0;m<4;m++)
        #pragma unroll
        for (int n=0;n<4;n++)
          acc[m][n] += a[m]*b[n];
    }
    __syncthreads();
  }
  #pragma unroll
  for (int m=0;m<4;m++){
    int gr = rowBase + ty*4 + m;
    if (gr>=M) continue;
    #pragma unroll
    for (int n=0;n<4;n++){
      int gc = colBase + tx*4 + n;
      if (gc>=N) continue;
      float v = acc[m][n];
      if (bias) v += bias[gc];
      if (act==1) v = geluf(v);
      else if (act==2) v = v*(1.f/(1.f+__expf(-1.702f*v)));
      if (res) v += res[(long long)gr*ldr + gc];
      out[(long long)gr*ldo + gc] = v;
    }
  }
}

// ---------- softmax in-place on bf16 scores ----------
__global__ __launch_bounds__(256)
void softmax_bf16(short* __restrict__ S, int ld, long long sS, int cols, float alpha,
                  const void* __restrict__ mask, long long maskoff, int maskld,
                  const int* __restrict__ modeflag)
{
  __shared__ float buf[2056];
  __shared__ float red[4];
  int row = blockIdx.x, z = blockIdx.y;
  short* p = S + (long long)z*sS + (long long)row*ld;
  int tid = threadIdx.x;
  int mode = 0;
  if (mask && modeflag) mode = *modeflag;
  float mx = -3.4e38f;
  for (int c=tid;c<cols;c+=256){
    float v = bff(p[c])*alpha;
    if (mask){
      long long mi = maskoff + (long long)row*maskld + c;
      bool ok = mode ? (((const unsigned char*)mask)[mi]!=0)
                     : (((const int*)mask)[mi]!=0);
      if (!ok) v = -3.4e38f;
    }
    buf[c] = v;
    mx = fmaxf(mx, v);
  }
  mx = wmaxr(mx);
  int wid = tid>>6, lane = tid&63;
  if (lane==0) red[wid]=mx;
  __syncthreads();
  mx = fmaxf(fmaxf(red[0],red[1]),fmaxf(red[2],red[3]));
  __syncthreads();
  float sum=0.f;
  for (int c=tid;c<cols;c+=256){
    float v = buf[c];
    float e = (v > -1.0e37f) ? __expf(v-mx) : 0.f;
    buf[c]=e; sum += e;
  }
  sum = wsum(sum);
  if (lane==0) red[wid]=sum;
  __syncthreads();
  sum = red[0]+red[1]+red[2]+red[3];
  float inv = 1.f/sum;
  for (int c=tid;c<cols;c+=256) p[c] = fbf(buf[c]*inv);
  for (int c=cols+tid;c<ld;c+=256) p[c] = 0;
}

// ---------- LayerNorm (fp32 in -> bf16 out), C=384 ----------
__global__ __launch_bounds__(128)
void ln_bf16_kernel(const float* __restrict__ in, const float* __restrict__ g,
                    const float* __restrict__ bt, short* __restrict__ out)
{
  long long row = blockIdx.x;
  const float* p = in + row*384;
  int tid = threadIdx.x;
  float v0=p[tid], v1=p[tid+128], v2=p[tid+256];
  float s = v0+v1+v2;
  float ss = v0*v0+v1*v1+v2*v2;
  __shared__ float r1[2], r2[2];
  s = wsum(s); ss = wsum(ss);
  int wid=tid>>6, lane=tid&63;
  if (lane==0){ r1[wid]=s; r2[wid]=ss; }
  __syncthreads();
  float mean=(r1[0]+r1[1])*(1.f/384.f);
  float var =(r2[0]+r2[1])*(1.f/384.f)-mean*mean;
  float rstd=rsqrtf(var+1e-5f);
  short* o = out + row*384;
  o[tid]     = fbf((v0-mean)*rstd*g[tid]+bt[tid]);
  o[tid+128] = fbf((v1-mean)*rstd*g[tid+128]+bt[tid+128]);
  o[tid+256] = fbf((v2-mean)*rstd*g[tid+256]+bt[tid+256]);
}

// ---------- fp32 -> bf16 convert (contiguous, vectorized) ----------
__global__ void cvt_kernel(const float* __restrict__ in, short* __restrict__ out, long long n4){
  long long i = (long long)blockIdx.x*256 + threadIdx.x;
  if (i<n4){
    float4 f = ((const float4*)in)[i];
    short4 s;
    s.x=fbf(f.x); s.y=fbf(f.y); s.z=fbf(f.z); s.w=fbf(f.w);
    ((short4*)out)[i]=s;
  }
}

// ---------- tiled transpose + convert: in fp32 [R,C] -> out bf16 [C, ldout] zero-padded ----------
__global__ __launch_bounds__(256)
void tconv_kernel(const float* __restrict__ in, int ldin, long long sIn, long long sIn2, int zmod,
                  int R, int C, short* __restrict__ out, int ldout, long long sOut)
{
  __shared__ float tile[32][33];
  int z = blockIdx.z;
  const float* ip = in + (long long)(z/zmod)*sIn + (long long)(z%zmod)*sIn2;
  short* op = out + (long long)z*sOut;
  int r0 = blockIdx.x*32;   // source-row tile (= out col)
  int c0 = blockIdx.y*32;   // source-col tile (= out row)
  int tx = threadIdx.x&31, ty = threadIdx.x>>5;
  #pragma unroll
  for (int i=0;i<4;i++){
    int r = r0 + ty + i*8, c = c0 + tx;
    tile[ty+i*8][tx] = (r<R && c<C) ? ip[(long long)r*ldin + c] : 0.f;
  }
  __syncthreads();
  #pragma unroll
  for (int i=0;i<4;i++){
    int oc = c0 + ty + i*8;
    int orr = r0 + tx;
    if (oc<C && orr<ldout) op[(long long)oc*ldout + orr] = fbf(tile[tx][ty+i*8]);
  }
}

// ---------- elementwise ----------
__global__ void ew_x2_kernel(float* x1, const float* ffn, const float* ada, long long n){
  long long i=(long long)blockIdx.x*256+threadIdx.x;
  if (i<n) x1[i] = x1[i] + ffn[i] + 0.5f*ada[i];
}
__global__ void copy_pts_kernel(const float* __restrict__ x2, float* __restrict__ pts){
  long long i=(long long)blockIdx.x*256+threadIdx.x;
  if (i < 8192ll*384){
    long long b = i/(2048ll*384);
    long long rem = i%(2048ll*384);
    pts[i] = x2[(b*2049+1)*384 + rem];
  }
}
__global__ void copy_cls_kernel(const float* __restrict__ x2, float* __restrict__ out){
  int i = blockIdx.x*256+threadIdx.x;
  if (i < 4*384){
    int b=i/384, c=i%384;
    out[(long long)b*2049*384 + c] = x2[(long long)b*2049*384 + c];
  }
}

// ---------- segment scatter (sum + max + count) ----------
__global__ __launch_bounds__(128)
void scatter_seg_kernel(const float* __restrict__ feat, const int* __restrict__ seg,
                        float* __restrict__ fsum, unsigned* __restrict__ fmax,
                        float* __restrict__ cnt)
{
  int n = blockIdx.x;
  int s = seg[n];
  const float* p = feat + (long long)n*384;
  int tid = threadIdx.x;
  #pragma unroll
  for (int k=0;k<3;k++){
    int c = tid + k*128;
    float v = p[c];
    atomicAdd(&fsum[(long long)s*384+c], v);
    atomicMax(&fmax[(long long)s*384+c], fkey(v));
  }
  if (tid==0) atomicAdd(&cnt[s], 1.0f);
}

// ---------- cell = bn_gelu(max + mean) ----------
__global__ __launch_bounds__(128)
void cell_kernel(const float* __restrict__ fsum, const unsigned* __restrict__ fmax,
                 const float* __restrict__ cnt,
                 const float* __restrict__ g, const float* __restrict__ bb,
                 const float* __restrict__ m, const float* __restrict__ v,
                 float* __restrict__ out)
{
  int s = blockIdx.x;
  float cn = cnt[s];
  float denom = fmaxf(cn, 1.f);
  int tid = threadIdx.x;
  #pragma unroll
  for (int k=0;k<3;k++){
    int c = tid + k*128;
    float mx = (cn>0.f) ? fdec(fmax[(long long)s*384+c]) : 0.f;
    float t = mx + fsum[(long long)s*384+c]/denom;
    t = (t - m[c])*rsqrtf(v[c]+1e-5f)*g[c] + bb[c];
    out[(long long)s*384+c] = geluf(t);
  }
}

// ---------- final cosine-sim weighted combine ----------
__global__ __launch_bounds__(128)
void combine_kernel(const float* __restrict__ pts, const float* __restrict__ cell3,
                    const int* __restrict__ cluster, const float* __restrict__ cell2,
                    const int* __restrict__ gidx, float* __restrict__ out)
{
  int n = blockIdx.x;
  int tid = threadIdx.x;
  __shared__ float sdot[6], ssq[6], sw[6];
  __shared__ int soff[6];
  __shared__ float red[2][2];
  __shared__ float sn3;
  const float* x3 = cell3 + (long long)cluster[n]*384;
  int wid=tid>>6, lane=tid&63;
  float sq=0.f;
  for (int c=tid;c<384;c+=128){ float v=x3[c]; sq+=v*v; }
  sq = wsum(sq);
  if (lane==0) red[0][wid]=sq;
  __syncthreads();
  if (tid==0) sn3 = sqrtf(red[0][0]+red[0][1]);
  __syncthreads();
  for (int i=0;i<6;i++){
    int gi = gidx[(long long)i*8192 + n];
    if (tid==0) soff[i]=gi;
    const float* r = cell2 + ((long long)i*4096 + gi)*384;
    float d=0.f, s2=0.f;
    for (int c=tid;c<384;c+=128){ float a=r[c]; d+=a*x3[c]; s2+=a*a; }
    d = wsum(d); s2 = wsum(s2);
    if (lane==0){ red[0][wid]=d; red[1][wid]=s2; }
    __syncthreads();
    if (tid==0){ sdot[i]=red[0][0]+red[0][1]; ssq[i]=red[1][0]+red[1][1]; }
    __syncthreads();
  }
  if (tid==0){
    float ssumv=0.f; float sims[6];
    for (int i=0;i<6;i++){
      float nrm = sqrtf(ssq[i])*sn3;
      float s = (sdot[i]/fmaxf(nrm,1e-8f) + 1.f)*0.5f;
      sims[i]=s; ssumv+=s;
    }
    for (int i=0;i<6;i++) sw[i]=sims[i]/ssumv;
  }
  __syncthreads();
  int b = n>>11, gp = n&2047;
  float* o = out + ((long long)(b*2049 + 1 + gp))*384;
  for (int c=tid;c<384;c+=128){
    float acc=0.f;
    #pragma unroll
    for (int i=0;i<6;i++){
      const float* r = cell2 + ((long long)i*4096 + soff[i])*384;
      acc += sw[i]*r[c];
    }
    o[c] = pts[(long long)n*384+c] + 0.5f*acc;
  }
}

// ---------- host helpers ----------
static inline void launch_gemm16(hipStream_t s, const short* A,int lda,long long sA,
  const short* B,int ldb,long long sB, const float* bias,
  const float* res,int ldr,long long sR, void* out,int ldo,long long sO,int outbf16,
  int M,int N,int K,int act,int nz,int KS)
{
  dim3 g((N+TBN-1)/TBN,(M+TBM-1)/TBM,(unsigned)(nz*KS));
  hipLaunchKernelGGL(gemm_bf16,g,dim3(256),0,s,
    A,lda,sA,B,ldb,sB,bias,res,ldr,sR,out,ldo,sO,outbf16,M,N,K,act,KS);
}
static inline void launch_gemmf(hipStream_t s, const float* A,int lda,long long sA,
  const float* W,int ldw,long long sW,int tW, const float* bias,
  const float* res,int ldr,long long sR, float* out,int ldo,long long sO,
  int M,int N,int K,int act,int nb)
{
  dim3 g((N+BN-1)/BN,(M+BM-1)/BM,nb);
  hipLaunchKernelGGL(gemm_f32,g,dim3(256),0,s,
    A,lda,sA,W,ldw,sW,tW,bias,res,ldr,sR,out,ldo,sO,M,N,K,act);
}
static inline void launch_tconv(hipStream_t s, const float* in,int ldin,long long sIn,long long sIn2,int zmod,
  int R,int C, short* out,int ldout,long long sOut,int nz)
{
  dim3 g((ldout+31)/32,(C+31)/32,(unsigned)nz);
  hipLaunchKernelGGL(tconv_kernel,g,dim3(256),0,s, in,ldin,sIn,sIn2,zmod,R,C,out,ldout,sOut);
}
static inline void launch_cvt(hipStream_t s, const float* in, short* out, long long n){
  long long n4 = n/4;
  hipLaunchKernelGGL(cvt_kernel,dim3((unsigned)((n4+255)/256)),dim3(256),0,s,in,out,n4);
}

extern "C" void kernel_launch(void* const* d_in, const int* in_sizes, int n_in,
                              void* d_out, int out_size, void* d_ws, size_t ws_size,
                              hipStream_t stream)
{
  const float* x       = (const float*)d_in[0];
  const float* norm1_g = (const float*)d_in[2];
  const float* norm1_b = (const float*)d_in[3];
  const float* qkv_w   = (const float*)d_in[4];
  const float* proj_w  = (const float*)d_in[5];
  const float* proj_b  = (const float*)d_in[6];
  const float* norm2_g = (const float*)d_in[7];
  const float* norm2_b = (const float*)d_in[8];
  const float* fc1_w   = (const float*)d_in[9];
  const float* fc1_b   = (const float*)d_in[10];
  const float* fc2_w   = (const float*)d_in[11];
  const float* fc2_b   = (const float*)d_in[12];
  const float* ada1_w  = (const float*)d_in[13];
  const float* ada1_b  = (const float*)d_in[14];
  const float* ada2_w  = (const float*)d_in[15];
  const float* ada2_b  = (const float*)d_in[16];
  const float* bn3_g   = (const float*)d_in[17];
  const float* bn3_b   = (const float*)d_in[18];
  const float* bn3_m   = (const float*)d_in[19];
  const float* bn3_v   = (const float*)d_in[20];
  const float* bn2_g   = (const float*)d_in[21];
  const float* bn2_b   = (const float*)d_in[22];
  const float* bn2_m   = (const float*)d_in[23];
  const float* bn2_v   = (const float*)d_in[24];
  const float* norm3_g = (const float*)d_in[25];
  const float* norm3_b = (const float*)d_in[26];
  const float* a1_qkv_w  = (const float*)d_in[27];
  const float* a1_proj_w = (const float*)d_in[28];
  const float* a1_proj_b = (const float*)d_in[29];
  const void*  maskp     = d_in[30];
  const int*   cluster   = (const int*)d_in[33];
  const int*   fgi       = (const int*)d_in[34];
  float* out = (float*)d_out;

  // ---- workspace layout ----
  size_t off = 0;
  char* wsb = (char*)d_ws;
  auto alloc = [&](size_t bytes)->void*{
    void* p = wsb + off;
    off += (bytes + 255) & ~(size_t)255;
    return p;
  };
  short*    bufHh = (short*)alloc(8196ll*384*2);
  float*    bufQ  = (float*)alloc(8196ll*1152*4);
  short*    bufQh = (short*)alloc(8196ll*1152*2);
  short*    Sb16  = (short*)alloc(6ll*2049*2056*2);
  short*    Vt    = (short*)alloc(24ll*64*2056*2);
  float*    bufO  = (float*)alloc(8196ll*384*4);
  short*    bufOh = (short*)alloc(8196ll*384*2);
  float*    bufX  = (float*)alloc(8196ll*384*4);
  float*    ptsb  = (float*)alloc(8192ll*384*4);
  float*    cnt   = (float*)alloc(1024*4);
  float*    fsum  = (float*)alloc(1024ll*384*4);
  unsigned* fmaxe = (unsigned*)alloc(1024ll*384*4);
  float*    cell3 = (float*)alloc(1024ll*384*4);
  float*    gc    = (float*)alloc(4096*4);
  float*    gsum  = (float*)alloc(4096ll*384*4);
  unsigned* gmaxe = (unsigned*)alloc(4096ll*384*4);
  float*    cell2 = (float*)alloc(6ll*4096*384*4);
  short*    qkvT  = (short*)alloc(1152ll*384*2);
  short*    projT = (short*)alloc(384ll*384*2);
  short*    fc1T  = (short*)alloc(1536ll*384*2);
  short*    fc2T  = (short*)alloc(384ll*1536*2);
  short*    a1qkvT  = (short*)alloc(6ll*1152*384*2);
  short*    a1projT = (short*)alloc(6ll*384*384*2);
  int*      flag  = (int*)alloc(256);
  // aliases (lifetime-disjoint):
  float* bufT   = (float*)Sb16;                          // a1_proj out, per view
  short* bufTh  = (short*)((char*)Sb16 + 13ll*1024*1024); // fc1 out (FFN window)
  float* bufAda = (float*)bufQh;                          // ada2 out (FFN window)
  float* bufA   = (float*)((char*)bufQh + 13ll*1024*1024);// ada1 out (FFN window)

  // ---- mask dtype detect ----
  hipMemsetAsync(flag, 0, 4, stream);
  {
    long long nInt = 6ll*2048*2048/4;
    detect_mask_kernel<<<dim3((unsigned)((nInt+255)/256)),dim3(256),0,stream>>>((const int*)maskp, nInt, flag);
  }

  // ---- weight transposes (fp32 [K,N] -> bf16 [N,K]) ----
  launch_tconv(stream, qkv_w, 1152, 0,0,1, 384,1152, qkvT, 384, 0, 1);
  launch_tconv(stream, proj_w, 384, 0,0,1, 384,384,  projT, 384, 0, 1);
  launch_tconv(stream, fc1_w, 1536, 0,0,1, 384,1536, fc1T, 384, 0, 1);
  launch_tconv(stream, fc2_w, 384,  0,0,1, 1536,384, fc2T, 1536, 0, 1);
  launch_tconv(stream, a1_qkv_w, 1152, 384ll*1152,0,1, 384,1152, a1qkvT, 384, 1152ll*384, 6);
  launch_tconv(stream, a1_proj_w, 384, 384ll*384,0,1, 384,384,  a1projT, 384, 384ll*384, 6);

  // ---- phase 1: transformer block ----
  ln_bf16_kernel<<<8196,128,0,stream>>>(x, norm1_g, norm1_b, bufHh);
  launch_gemm16(stream, bufHh,384,0, qkvT,384,0, nullptr, nullptr,0,0,
                bufQ,1152,0,0, 8196,1152,384, 0, 1,1);
  launch_cvt(stream, bufQ, bufQh, 8196ll*1152);
  // V^T for inner attention: z=(b*6+h), in [2049x64] -> out [64][2056]
  launch_tconv(stream, bufQ + 768, 1152, 2049ll*1152, 64, 6, 2049, 64, Vt, 2056, 64ll*2056, 24);
  hipMemsetAsync(bufO, 0, 8196ll*384*4, stream);
  for (int b=0;b<4;b++){
    const short* qb = bufQh + (long long)b*2049*1152;
    launch_gemm16(stream, qb,1152,64, qb+384,1152,64, nullptr, nullptr,0,0,
                  Sb16,2056,2049ll*2056,1, 2049,2049,64, 0, 6,1);
    softmax_bf16<<<dim3(2049,6),256,0,stream>>>(Sb16,2056,2049ll*2056,2049,0.125f,
                                                nullptr,0,0,nullptr);
    launch_gemm16(stream, Sb16,2056,2049ll*2056, Vt + (long long)b*6*64*2056,2056,64ll*2056,
                  nullptr, nullptr,0,0,
                  bufO + (long long)b*2049*384,384,64,0, 2049,64,2056, 0, 6,8);
  }
  launch_cvt(stream, bufO, bufOh, 8196ll*384);
  launch_gemm16(stream, bufOh,384,0, projT,384,0, proj_b, x,384,0,
                bufX,384,0,0, 8196,384,384, 0, 1,1);
  ln_bf16_kernel<<<8196,128,0,stream>>>(bufX, norm2_g, norm2_b, bufHh);
  launch_gemm16(stream, bufHh,384,0, fc1T,384,0, fc1_b, nullptr,0,0,
                bufTh,1536,0,1, 8196,1536,384, 1, 1,1);
  launch_gemm16(stream, bufTh,1536,0, fc2T,1536,0, fc2_b, nullptr,0,0,
                bufO,384,0,0, 8196,384,1536, 0, 1,1);
  launch_gemmf(stream, bufO,384,0, ada1_w,96,0,0, ada1_b, nullptr,0,0,
               bufA,96,0, 8196,96,384, 2, 1);
  launch_gemmf(stream, bufA,96,0, ada2_w,384,0,0, ada2_b, nullptr,0,0,
               bufAda,384,0, 8196,384,96, 0, 1);
  ew_x2_kernel<<<dim3((8196*384+255)/256),256,0,stream>>>(bufX, bufO, bufAda, 8196ll*384);
  copy_cls_kernel<<<6,256,0,stream>>>(bufX, out);
  copy_pts_kernel<<<dim3((8192*384+255)/256),256,0,stream>>>(bufX, ptsb);

  // ---- phase 2: cluster pooling -> cell3 ----
  hipMemsetAsync(cnt, 0, 1024*4, stream);
  hipMemsetAsync(fsum, 0, 1024ll*384*4, stream);
  hipMemsetAsync(fmaxe, 0, 1024ll*384*4, stream);
  scatter_seg_kernel<<<8192,128,0,stream>>>(ptsb, cluster, fsum, fmaxe, cnt);
  cell_kernel<<<1024,128,0,stream>>>(fsum, fmaxe, cnt, bn3_g,bn3_b,bn3_m,bn3_v, cell3);

  // ---- phase 3: views ----
  for (int i=0;i<6;i++){
    ln_bf16_kernel<<<8192,128,0,stream>>>(ptsb, norm3_g + (long long)i*384, norm3_b + (long long)i*384, bufHh);
    launch_gemm16(stream, bufHh,384,0, a1qkvT + (long long)i*1152*384,384,0,
                  nullptr, nullptr,0,0, bufQ,1152,0,0, 8192,1152,384, 0, 1,1);
    launch_cvt(stream, bufQ, bufQh, 8192ll*1152);
    launch_tconv(stream, bufQ + 768, 1152, 2048ll*1152, 0, 1, 2048, 384, Vt, 2048, 384ll*2048, 4);
    launch_gemm16(stream, bufQh,1152,2048ll*1152, bufQh+384,1152,2048ll*1152,
                  nullptr, nullptr,0,0, Sb16,2048,2048ll*2048,1, 2048,2048,384, 0, 4,1);
    softmax_bf16<<<dim3(2048,4),256,0,stream>>>(Sb16,2048,2048ll*2048,2048,
                0.05103103630798288f, maskp, (long long)i*2048*2048, 2048, flag);
    hipMemsetAsync(bufO, 0, 8192ll*384*4, stream);
    launch_gemm16(stream, Sb16,2048,2048ll*2048, Vt,2048,384ll*2048,
                  nullptr, nullptr,0,0, bufO,384,2048ll*384,0, 2048,384,2048, 0, 4,2);
    launch_cvt(stream, bufO, bufOh, 8192ll*384);
    launch_gemm16(stream, bufOh,384,0, a1projT + (long long)i*384*384,384,0,
                  a1_proj_b + (long long)i*384, ptsb,384,0,
                  bufT,384,0,0, 8192,384,384, 0, 1,1);
    hipMemsetAsync(gc, 0, 4096*4, stream);
    hipMemsetAsync(gsum, 0, 4096ll*384*4, stream);
    hipMemsetAsync(gmaxe, 0, 4096ll*384*4, stream);
    scatter_seg_kernel<<<8192,128,0,stream>>>(bufT, fgi + (long long)i*8192, gsum, gmaxe, gc);
    cell_kernel<<<4096,128,0,stream>>>(gsum, gmaxe, gc,
        bn2_g + (long long)i*384, bn2_b + (long long)i*384,
        bn2_m + (long long)i*384, bn2_v + (long long)i*384,
        cell2 + (long long)i*4096*384);
  }

  // ---- phase 4: combine ----
  combine_kernel<<<8192,128,0,stream>>>(ptsb, cell3, cluster, cell2, fgi, out);
}

// Round 3
// 2473.776 us; speedup vs baseline: 4.8240x; 1.0503x over previous
//
#include <hip/hip_runtime.h>
#include <math.h>

typedef short bf16x8 __attribute__((ext_vector_type(8)));
typedef float f32x4 __attribute__((ext_vector_type(4)));

#define GLL16(g, l) \
  __builtin_amdgcn_global_load_lds((__attribute__((address_space(1))) const unsigned int*)(g), \
                                   (__attribute__((address_space(3))) unsigned int*)(l), 16, 0, 0)

// ---------- helpers ----------
__device__ __forceinline__ float wsum(float v){
  #pragma unroll
  for (int o=32;o;o>>=1) v += __shfl_xor(v,o);
  return v;
}
__device__ __forceinline__ float wmaxr(float v){
  #pragma unroll
  for (int o=32;o;o>>=1) v = fmaxf(v,__shfl_xor(v,o));
  return v;
}
__device__ __forceinline__ float geluf(float x){
  return 0.5f*x*(1.0f+erff(x*0.7071067811865475f));
}
__device__ __forceinline__ short fbf(float f){   // fp32 -> bf16 RNE
  unsigned u = __float_as_uint(f);
  unsigned r = (u + 0x7fffu + ((u>>16)&1u)) >> 16;
  return (short)r;
}
__device__ __forceinline__ float bff(short s){
  return __uint_as_float(((unsigned)(unsigned short)s)<<16);
}
__device__ __forceinline__ unsigned fkey(float f){
  unsigned b=__float_as_uint(f);
  return (b&0x80000000u)? ~b : (b|0x80000000u);
}
__device__ __forceinline__ float fdec(unsigned k){
  unsigned b=(k&0x80000000u)? (k&0x7fffffffu) : ~k;
  return __uint_as_float(b);
}

// ---------- mask dtype detection ----------
__global__ void detect_mask_kernel(const int* __restrict__ m, long long n, int* flag){
  long long i = (long long)blockIdx.x*256 + threadIdx.x;
  bool bad = (i<n) && (m[i]!=0 && m[i]!=1);
  if (__any(bad)) { if ((threadIdx.x&63)==0) atomicOr(flag,1); }
}

// ---------- bf16 MFMA GEMM with global_load_lds staging ----------
// out[z] = epilogue( A[z] @ B[z]^T )   A:[M,K] bf16 lda, B:[N,K] bf16 ldb.
// REQUIRES: K % 32 == 0, lda/ldb multiples of 8, base pointers 16B-aligned.
// KS>1: split-K, atomicAdd fp32 into pre-zeroed out (no epilogue).
// LDS layout (per 16-row block, 1KB): chunk addr = quad*256B + row_in_blk*16B,
// which is exactly lane-linear for global_load_lds (lane = quad*16 + lm).
#define TBM 128
#define TBN 64
#define TBK 32
__global__ __launch_bounds__(256)
void gemm_bf16(const short* __restrict__ A, int lda, long long sA,
               const short* __restrict__ B, int ldb, long long sB,
               const float* __restrict__ bias,
               const float* __restrict__ res, int ldr, long long sR,
               void* __restrict__ out, int ldo, long long sO, int outbf16,
               int M, int N, int K, int act, int KS)
{
  __shared__ short As[TBM*TBK];   // 8 KB
  __shared__ short Bs[TBN*TBK];   // 4 KB
  int zz = blockIdx.z;
  int z = zz / KS, ks = zz - z*KS;
  A += (long long)z*sA; B += (long long)z*sB;
  if (res) res += (long long)z*sR;
  float* outF = (float*)out + (long long)z*sO;
  short* outH = (short*)out + (long long)z*sO;

  int tid = threadIdx.x;
  int rowBase = blockIdx.y*TBM;
  int colBase = blockIdx.x*TBN;

  int Kc = ((K + KS*TBK - 1)/(KS*TBK))*TBK;
  int kbeg = ks*Kc;
  int kend = min(K, kbeg+Kc);
  if (kbeg >= kend) return;

  int w = tid>>6;
  int lane = tid&63;
  int lm = lane&15, quad = lane>>4;
  int waveM = w>>1, waveN = w&1;

  // staging addresses: wave w loads A blocks (w*2, w*2+1) and B block w
  int arow0 = min(rowBase + w*32 + lm,      M-1);
  int arow1 = min(rowBase + w*32 + 16 + lm, M-1);
  int brow  = min(colBase + w*16 + lm,      N-1);
  const short* Ag0 = A + (long long)arow0*lda + quad*8;
  const short* Ag1 = A + (long long)arow1*lda + quad*8;
  const short* Bg  = B + (long long)brow*ldb  + quad*8;
  short* Al0 = &As[(w*2+0)*512];
  short* Al1 = &As[(w*2+1)*512];
  short* Bl  = &Bs[w*512];

  f32x4 acc[4][2] = {};

  for (int k0=kbeg; k0<kend; k0+=TBK){
    GLL16(Ag0 + k0, Al0);
    GLL16(Ag1 + k0, Al1);
    GLL16(Bg  + k0, Bl);
    __syncthreads();
    bf16x8 af[4], bfr[2];
    #pragma unroll
    for (int tm=0;tm<4;tm++) af[tm]  = *(bf16x8*)&As[(waveM*4+tm)*512 + quad*128 + lm*8];
    #pragma unroll
    for (int tn=0;tn<2;tn++) bfr[tn] = *(bf16x8*)&Bs[(waveN*2+tn)*512 + quad*128 + lm*8];
    #pragma unroll
    for (int tm=0;tm<4;tm++)
      #pragma unroll
      for (int tn=0;tn<2;tn++)
        acc[tm][tn] = __builtin_amdgcn_mfma_f32_16x16x32_bf16(af[tm], bfr[tn], acc[tm][tn], 0,0,0);
    __syncthreads();
  }

  #pragma unroll
  for (int tm=0;tm<4;tm++){
    #pragma unroll
    for (int tn=0;tn<2;tn++){
      int col = colBase + waveN*32 + tn*16 + lm;
      if (col>=N) continue;
      #pragma unroll
      for (int reg=0;reg<4;reg++){
        int row = rowBase + waveM*64 + tm*16 + quad*4 + reg;
        if (row>=M) continue;
        float v = acc[tm][tn][reg];
        if (KS>1){ atomicAdd(&outF[(long long)row*ldo+col], v); continue; }
        if (bias) v += bias[col];
        if (act==1) v = geluf(v);
        else if (act==2) v = v*(1.f/(1.f+__expf(-1.702f*v)));
        if (res) v += res[(long long)row*ldr+col];
        if (outbf16) outH[(long long)row*ldo+col] = fbf(v);
        else         outF[(long long)row*ldo+col] = v;
      }
    }
  }
}

// ---------- softmax in-place on bf16 scores ----------
__global__ __launch_bounds__(256)
void softmax_bf16(short* __restrict__ S, int ld, long long sS, int cols, float alpha,
                  const void* __restrict__ mask, long long maskoff, int maskld,
                  const int* __restrict__ modeflag)
{
  __shared__ float buf[2080];
  __shared__ float red[4];
  int row = blockIdx.x, z = blockIdx.y;
  short* p = S + (long long)z*sS + (long long)row*ld;
  int tid = threadIdx.x;
  int mode = 0;
  if (mask && modeflag) mode = *modeflag;
  float mx = -3.4e38f;
  for (int c=tid;c<cols;c+=256){
    float v = bff(p[c])*alpha;
    if (mask){
      long long mi = maskoff + (long long)row*maskld + c;
      bool ok = mode ? (((const unsigned char*)mask)[mi]!=0)
                     : (((const int*)mask)[mi]!=0);
      if (!ok) v = -3.4e38f;
    }
    buf[c] = v;
    mx = fmaxf(mx, v);
  }
  mx = wmaxr(mx);
  int wid = tid>>6, lane = tid&63;
  if (lane==0) red[wid]=mx;
  __syncthreads();
  mx = fmaxf(fmaxf(red[0],red[1]),fmaxf(red[2],red[3]));
  __syncthreads();
  float sum=0.f;
  for (int c=tid;c<cols;c+=256){
    float v = buf[c];
    float e = (v > -1.0e37f) ? __expf(v-mx) : 0.f;
    buf[c]=e; sum += e;
  }
  sum = wsum(sum);
  if (lane==0) red[wid]=sum;
  __syncthreads();
  sum = red[0]+red[1]+red[2]+red[3];
  float inv = 1.f/sum;
  for (int c=tid;c<cols;c+=256) p[c] = fbf(buf[c]*inv);
  for (int c=cols+tid;c<ld;c+=256) p[c] = 0;
}

// ---------- LayerNorm (fp32 in -> bf16 out), C=384 ----------
__global__ __launch_bounds__(128)
void ln_bf16_kernel(const float* __restrict__ in, const float* __restrict__ g,
                    const float* __restrict__ bt, short* __restrict__ out)
{
  long long row = blockIdx.x;
  const float* p = in + row*384;
  int tid = threadIdx.x;
  float v0=p[tid], v1=p[tid+128], v2=p[tid+256];
  float s = v0+v1+v2;
  float ss = v0*v0+v1*v1+v2*v2;
  __shared__ float r1[2], r2[2];
  s = wsum(s); ss = wsum(ss);
  int wid=tid>>6, lane=tid&63;
  if (lane==0){ r1[wid]=s; r2[wid]=ss; }
  __syncthreads();
  float mean=(r1[0]+r1[1])*(1.f/384.f);
  float var =(r2[0]+r2[1])*(1.f/384.f)-mean*mean;
  float rstd=rsqrtf(var+1e-5f);
  short* o = out + row*384;
  o[tid]     = fbf((v0-mean)*rstd*g[tid]+bt[tid]);
  o[tid+128] = fbf((v1-mean)*rstd*g[tid+128]+bt[tid+128]);
  o[tid+256] = fbf((v2-mean)*rstd*g[tid+256]+bt[tid+256]);
}

// ---------- fp32 -> bf16 convert ----------
__global__ void cvt_kernel(const float* __restrict__ in, short* __restrict__ out, long long n4){
  long long i = (long long)blockIdx.x*256 + threadIdx.x;
  if (i<n4){
    float4 f = ((const float4*)in)[i];
    short4 s;
    s.x=fbf(f.x); s.y=fbf(f.y); s.z=fbf(f.z); s.w=fbf(f.w);
    ((short4*)out)[i]=s;
  }
}

// ---------- tiled transpose+convert: fp32 [R,C] -> bf16 [C, ldout] zero-padded ----------
__global__ __launch_bounds__(256)
void tconv_kernel(const float* __restrict__ in, int ldin, long long sIn, long long sIn2, int zmod,
                  int R, int C, short* __restrict__ out, int ldout, long long sOut)
{
  __shared__ float tile[32][33];
  int z = blockIdx.z;
  const float* ip = in + (long long)(z/zmod)*sIn + (long long)(z%zmod)*sIn2;
  short* op = out + (long long)z*sOut;
  int r0 = blockIdx.x*32;
  int c0 = blockIdx.y*32;
  int tx = threadIdx.x&31, ty = threadIdx.x>>5;
  #pragma unroll
  for (int i=0;i<4;i++){
    int r = r0 + ty + i*8, c = c0 + tx;
    tile[ty+i*8][tx] = (r<R && c<C) ? ip[(long long)r*ldin + c] : 0.f;
  }
  __syncthreads();
  #pragma unroll
  for (int i=0;i<4;i++){
    int oc = c0 + ty + i*8;
    int orr = r0 + tx;
    if (oc<C && orr<ldout) op[(long long)oc*ldout + orr] = fbf(tile[tx][ty+i*8]);
  }
}

// ---------- tiled transpose: bf16 [R,C] -> bf16 [C, ldout] zero-padded ----------
__global__ __launch_bounds__(256)
void tconv16_kernel(const short* __restrict__ in, int ldin, long long sIn, long long sIn2, int zmod,
                    int R, int C, short* __restrict__ out, int ldout, long long sOut)
{
  __shared__ short tile[32][34];
  int z = blockIdx.z;
  const short* ip = in + (long long)(z/zmod)*sIn + (long long)(z%zmod)*sIn2;
  short* op = out + (long long)z*sOut;
  int r0 = blockIdx.x*32;
  int c0 = blockIdx.y*32;
  int tx = threadIdx.x&31, ty = threadIdx.x>>5;
  #pragma unroll
  for (int i=0;i<4;i++){
    int r = r0 + ty + i*8, c = c0 + tx;
    tile[ty+i*8][tx] = (r<R && c<C) ? ip[(long long)r*ldin + c] : (short)0;
  }
  __syncthreads();
  #pragma unroll
  for (int i=0;i<4;i++){
    int oc = c0 + ty + i*8;
    int orr = r0 + tx;
    if (oc<C && orr<ldout) op[(long long)oc*ldout + orr] = tile[tx][ty+i*8];
  }
}

// ---------- elementwise ----------
__global__ void ew_x2_kernel(float* x1, const float* ffn, const float* ada, long long n){
  long long i=(long long)blockIdx.x*256+threadIdx.x;
  if (i<n) x1[i] = x1[i] + ffn[i] + 0.5f*ada[i];
}
__global__ void copy_pts_kernel(const float* __restrict__ x2, float* __restrict__ pts){
  long long i=(long long)blockIdx.x*256+threadIdx.x;
  if (i < 8192ll*384){
    long long b = i/(2048ll*384);
    long long rem = i%(2048ll*384);
    pts[i] = x2[(b*2049+1)*384 + rem];
  }
}
__global__ void copy_cls_kernel(const float* __restrict__ x2, float* __restrict__ out){
  int i = blockIdx.x*256+threadIdx.x;
  if (i < 4*384){
    int b=i/384, c=i%384;
    out[(long long)b*2049*384 + c] = x2[(long long)b*2049*384 + c];
  }
}

// ---------- segment scatter (sum + max + count) ----------
__global__ __launch_bounds__(128)
void scatter_seg_kernel(const float* __restrict__ feat, const int* __restrict__ seg,
                        float* __restrict__ fsum, unsigned* __restrict__ fmax,
                        float* __restrict__ cnt)
{
  int n = blockIdx.x;
  int s = seg[n];
  const float* p = feat + (long long)n*384;
  int tid = threadIdx.x;
  #pragma unroll
  for (int k=0;k<3;k++){
    int c = tid + k*128;
    float v = p[c];
    atomicAdd(&fsum[(long long)s*384+c], v);
    atomicMax(&fmax[(long long)s*384+c], fkey(v));
  }
  if (tid==0) atomicAdd(&cnt[s], 1.0f);
}

// ---------- cell = bn_gelu(max + mean) ----------
__global__ __launch_bounds__(128)
void cell_kernel(const float* __restrict__ fsum, const unsigned* __restrict__ fmax,
                 const float* __restrict__ cnt,
                 const float* __restrict__ g, const float* __restrict__ bb,
                 const float* __restrict__ m, const float* __restrict__ v,
                 float* __restrict__ out)
{
  int s = blockIdx.x;
  float cn = cnt[s];
  float denom = fmaxf(cn, 1.f);
  int tid = threadIdx.x;
  #pragma unroll
  for (int k=0;k<3;k++){
    int c = tid + k*128;
    float mx = (cn>0.f) ? fdec(fmax[(long long)s*384+c]) : 0.f;
    float t = mx + fsum[(long long)s*384+c]/denom;
    t = (t - m[c])*rsqrtf(v[c]+1e-5f)*g[c] + bb[c];
    out[(long long)s*384+c] = geluf(t);
  }
}

// ---------- final cosine-sim weighted combine ----------
__global__ __launch_bounds__(128)
void combine_kernel(const float* __restrict__ pts, const float* __restrict__ cell3,
                    const int* __restrict__ cluster, const float* __restrict__ cell2,
                    const int* __restrict__ gidx, float* __restrict__ out)
{
  int n = blockIdx.x;
  int tid = threadIdx.x;
  __shared__ float sdot[6], ssq[6], sw[6];
  __shared__ int soff[6];
  __shared__ float red[2][2];
  __shared__ float sn3;
  const float* x3 = cell3 + (long long)cluster[n]*384;
  int wid=tid>>6, lane=tid&63;
  float sq=0.f;
  for (int c=tid;c<384;c+=128){ float v=x3[c]; sq+=v*v; }
  sq = wsum(sq);
  if (lane==0) red[0][wid]=sq;
  __syncthreads();
  if (tid==0) sn3 = sqrtf(red[0][0]+red[0][1]);
  __syncthreads();
  for (int i=0;i<6;i++){
    int gi = gidx[(long long)i*8192 + n];
    if (tid==0) soff[i]=gi;
    const float* r = cell2 + ((long long)i*4096 + gi)*384;
    float d=0.f, s2=0.f;
    for (int c=tid;c<384;c+=128){ float a=r[c]; d+=a*x3[c]; s2+=a*a; }
    d = wsum(d); s2 = wsum(s2);
    if (lane==0){ red[0][wid]=d; red[1][wid]=s2; }
    __syncthreads();
    if (tid==0){ sdot[i]=red[0][0]+red[0][1]; ssq[i]=red[1][0]+red[1][1]; }
    __syncthreads();
  }
  if (tid==0){
    float ssumv=0.f; float sims[6];
    for (int i=0;i<6;i++){
      float nrm = sqrtf(ssq[i])*sn3;
      float s = (sdot[i]/fmaxf(nrm,1e-8f) + 1.f)*0.5f;
      sims[i]=s; ssumv+=s;
    }
    for (int i=0;i<6;i++) sw[i]=sims[i]/ssumv;
  }
  __syncthreads();
  int b = n>>11, gp = n&2047;
  float* o = out + ((long long)(b*2049 + 1 + gp))*384;
  for (int c=tid;c<384;c+=128){
    float acc=0.f;
    #pragma unroll
    for (int i=0;i<6;i++){
      const float* r = cell2 + ((long long)i*4096 + soff[i])*384;
      acc += sw[i]*r[c];
    }
    o[c] = pts[(long long)n*384+c] + 0.5f*acc;
  }
}

// ---------- host helpers ----------
static inline void launch_gemm16(hipStream_t s, const short* A,int lda,long long sA,
  const short* B,int ldb,long long sB, const float* bias,
  const float* res,int ldr,long long sR, void* out,int ldo,long long sO,int outbf16,
  int M,int N,int K,int act,int nz,int KS)
{
  dim3 g((N+TBN-1)/TBN,(M+TBM-1)/TBM,(unsigned)(nz*KS));
  hipLaunchKernelGGL(gemm_bf16,g,dim3(256),0,s,
    A,lda,sA,B,ldb,sB,bias,res,ldr,sR,out,ldo,sO,outbf16,M,N,K,act,KS);
}
static inline void launch_tconv(hipStream_t s, const float* in,int ldin,long long sIn,long long sIn2,int zmod,
  int R,int C, short* out,int ldout,long long sOut,int nz)
{
  dim3 g((ldout+31)/32,(C+31)/32,(unsigned)nz);
  hipLaunchKernelGGL(tconv_kernel,g,dim3(256),0,s, in,ldin,sIn,sIn2,zmod,R,C,out,ldout,sOut);
}
static inline void launch_tconv16(hipStream_t s, const short* in,int ldin,long long sIn,long long sIn2,int zmod,
  int R,int C, short* out,int ldout,long long sOut,int nz)
{
  dim3 g((ldout+31)/32,(C+31)/32,(unsigned)nz);
  hipLaunchKernelGGL(tconv16_kernel,g,dim3(256),0,s, in,ldin,sIn,sIn2,zmod,R,C,out,ldout,sOut);
}
static inline void launch_cvt(hipStream_t s, const float* in, short* out, long long n){
  long long n4 = n/4;
  hipLaunchKernelGGL(cvt_kernel,dim3((unsigned)((n4+255)/256)),dim3(256),0,s,in,out,n4);
}

extern "C" void kernel_launch(void* const* d_in, const int* in_sizes, int n_in,
                              void* d_out, int out_size, void* d_ws, size_t ws_size,
                              hipStream_t stream)
{
  const float* x       = (const float*)d_in[0];
  const float* norm1_g = (const float*)d_in[2];
  const float* norm1_b = (const float*)d_in[3];
  const float* qkv_w   = (const float*)d_in[4];
  const float* proj_w  = (const float*)d_in[5];
  const float* proj_b  = (const float*)d_in[6];
  const float* norm2_g = (const float*)d_in[7];
  const float* norm2_b = (const float*)d_in[8];
  const float* fc1_w   = (const float*)d_in[9];
  const float* fc1_b   = (const float*)d_in[10];
  const float* fc2_w   = (const float*)d_in[11];
  const float* fc2_b   = (const float*)d_in[12];
  const float* ada1_w  = (const float*)d_in[13];
  const float* ada1_b  = (const float*)d_in[14];
  const float* ada2_w  = (const float*)d_in[15];
  const float* ada2_b  = (const float*)d_in[16];
  const float* bn3_g   = (const float*)d_in[17];
  const float* bn3_b   = (const float*)d_in[18];
  const float* bn3_m   = (const float*)d_in[19];
  const float* bn3_v   = (const float*)d_in[20];
  const float* bn2_g   = (const float*)d_in[21];
  const float* bn2_b   = (const float*)d_in[22];
  const float* bn2_m   = (const float*)d_in[23];
  const float* bn2_v   = (const float*)d_in[24];
  const float* norm3_g = (const float*)d_in[25];
  const float* norm3_b = (const float*)d_in[26];
  const float* a1_qkv_w  = (const float*)d_in[27];
  const float* a1_proj_w = (const float*)d_in[28];
  const float* a1_proj_b = (const float*)d_in[29];
  const void*  maskp     = d_in[30];
  const int*   cluster   = (const int*)d_in[33];
  const int*   fgi       = (const int*)d_in[34];
  float* out = (float*)d_out;

  // ---- workspace layout ----
  size_t off = 0;
  char* wsb = (char*)d_ws;
  auto alloc = [&](size_t bytes)->void*{
    void* p = wsb + off;
    off += (bytes + 255) & ~(size_t)255;
    return p;
  };
  short*    bufHh = (short*)alloc(8196ll*384*2);
  short*    bufQh = (short*)alloc(8196ll*1152*2);
  short*    Sb16  = (short*)alloc(6ll*2049*2080*2);
  short*    Vt    = (short*)alloc(24ll*64*2080*2);
  float*    bufO  = (float*)alloc(8196ll*384*4);
  short*    bufOh = (short*)alloc(8196ll*384*2);
  short*    bufAh = (short*)alloc(8196ll*96*2);
  float*    bufX  = (float*)alloc(8196ll*384*4);
  float*    ptsb  = (float*)alloc(8192ll*384*4);
  float*    cnt   = (float*)alloc(1024*4);
  float*    fsum  = (float*)alloc(1024ll*384*4);
  unsigned* fmaxe = (unsigned*)alloc(1024ll*384*4);
  float*    cell3 = (float*)alloc(1024ll*384*4);
  float*    gc    = (float*)alloc(4096*4);
  float*    gsum  = (float*)alloc(4096ll*384*4);
  unsigned* gmaxe = (unsigned*)alloc(4096ll*384*4);
  float*    cell2 = (float*)alloc(6ll*4096*384*4);
  short*    qkvT  = (short*)alloc(1152ll*384*2);
  short*    projT = (short*)alloc(384ll*384*2);
  short*    fc1T  = (short*)alloc(1536ll*384*2);
  short*    fc2T  = (short*)alloc(384ll*1536*2);
  short*    ada1T = (short*)alloc(96ll*384*2);
  short*    ada2T = (short*)alloc(384ll*96*2);
  short*    a1qkvT  = (short*)alloc(6ll*1152*384*2);
  short*    a1projT = (short*)alloc(6ll*384*384*2);
  int*      flag  = (int*)alloc(256);
  // aliases (lifetime-disjoint):
  float* bufT   = (float*)Sb16;                             // a1_proj out, per view
  short* bufTh  = (short*)((char*)Sb16 + 14ll*1024*1024);   // fc1 out (FFN window)
  float* bufAda = (float*)bufQh;                            // ada2 out (FFN window)

  // ---- mask dtype detect ----
  hipMemsetAsync(flag, 0, 4, stream);
  {
    long long nInt = 6ll*2048*2048/4;
    detect_mask_kernel<<<dim3((unsigned)((nInt+255)/256)),dim3(256),0,stream>>>((const int*)maskp, nInt, flag);
  }

  // ---- weight transposes (fp32 [K,N] -> bf16 [N,K]) ----
  launch_tconv(stream, qkv_w, 1152, 0,0,1, 384,1152, qkvT, 384, 0, 1);
  launch_tconv(stream, proj_w, 384, 0,0,1, 384,384,  projT, 384, 0, 1);
  launch_tconv(stream, fc1_w, 1536, 0,0,1, 384,1536, fc1T, 384, 0, 1);
  launch_tconv(stream, fc2_w, 384,  0,0,1, 1536,384, fc2T, 1536, 0, 1);
  launch_tconv(stream, ada1_w, 96,  0,0,1, 384,96,   ada1T, 384, 0, 1);
  launch_tconv(stream, ada2_w, 384, 0,0,1, 96,384,   ada2T, 96, 0, 1);
  launch_tconv(stream, a1_qkv_w, 1152, 384ll*1152,0,1, 384,1152, a1qkvT, 384, 1152ll*384, 6);
  launch_tconv(stream, a1_proj_w, 384, 384ll*384,0,1, 384,384,  a1projT, 384, 384ll*384, 6);

  // ---- phase 1: transformer block ----
  ln_bf16_kernel<<<8196,128,0,stream>>>(x, norm1_g, norm1_b, bufHh);
  launch_gemm16(stream, bufHh,384,0, qkvT,384,0, nullptr, nullptr,0,0,
                bufQh,1152,0,1, 8196,1152,384, 0, 1,1);
  // V^T for inner attention: z=(b*6+h), in bf16 [2049x64] slice -> out [64][2080]
  launch_tconv16(stream, bufQh + 768, 1152, 2049ll*1152, 64, 6, 2049, 64, Vt, 2080, 64ll*2080, 24);
  hipMemsetAsync(bufO, 0, 8196ll*384*4, stream);
  for (int b=0;b<4;b++){
    const short* qb = bufQh + (long long)b*2049*1152;
    launch_gemm16(stream, qb,1152,64, qb+384,1152,64, nullptr, nullptr,0,0,
                  Sb16,2080,2049ll*2080,1, 2049,2049,64, 0, 6,1);
    softmax_bf16<<<dim3(2049,6),256,0,stream>>>(Sb16,2080,2049ll*2080,2049,0.125f,
                                                nullptr,0,0,nullptr);
    launch_gemm16(stream, Sb16,2080,2049ll*2080, Vt + (long long)b*6*64*2080,2080,64ll*2080,
                  nullptr, nullptr,0,0,
                  bufO + (long long)b*2049*384,384,64,0, 2049,64,2080, 0, 6,8);
  }
  launch_cvt(stream, bufO, bufOh, 8196ll*384);
  launch_gemm16(stream, bufOh,384,0, projT,384,0, proj_b, x,384,0,
                bufX,384,0,0, 8196,384,384, 0, 1,1);
  ln_bf16_kernel<<<8196,128,0,stream>>>(bufX, norm2_g, norm2_b, bufHh);
  launch_gemm16(stream, bufHh,384,0, fc1T,384,0, fc1_b, nullptr,0,0,
                bufTh,1536,0,1, 8196,1536,384, 1, 1,1);
  launch_gemm16(stream, bufTh,1536,0, fc2T,1536,0, fc2_b, nullptr,0,0,
                bufO,384,0,0, 8196,384,1536, 0, 1,1);
  launch_cvt(stream, bufO, bufOh, 8196ll*384);
  launch_gemm16(stream, bufOh,384,0, ada1T,384,0, ada1_b, nullptr,0,0,
                bufAh,96,0,1, 8196,96,384, 2, 1,1);
  launch_gemm16(stream, bufAh,96,0, ada2T,96,0, ada2_b, nullptr,0,0,
                bufAda,384,0,0, 8196,384,96, 0, 1,1);
  ew_x2_kernel<<<dim3((8196*384+255)/256),256,0,stream>>>(bufX, bufO, bufAda, 8196ll*384);
  copy_cls_kernel<<<6,256,0,stream>>>(bufX, out);
  copy_pts_kernel<<<dim3((8192*384+255)/256),256,0,stream>>>(bufX, ptsb);

  // ---- phase 2: cluster pooling -> cell3 ----
  hipMemsetAsync(cnt, 0, 1024*4, stream);
  hipMemsetAsync(fsum, 0, 1024ll*384*4, stream);
  hipMemsetAsync(fmaxe, 0, 1024ll*384*4, stream);
  scatter_seg_kernel<<<8192,128,0,stream>>>(ptsb, cluster, fsum, fmaxe, cnt);
  cell_kernel<<<1024,128,0,stream>>>(fsum, fmaxe, cnt, bn3_g,bn3_b,bn3_m,bn3_v, cell3);

  // ---- phase 3: views ----
  for (int i=0;i<6;i++){
    ln_bf16_kernel<<<8192,128,0,stream>>>(ptsb, norm3_g + (long long)i*384, norm3_b + (long long)i*384, bufHh);
    launch_gemm16(stream, bufHh,384,0, a1qkvT + (long long)i*1152*384,384,0,
                  nullptr, nullptr,0,0, bufQh,1152,0,1, 8192,1152,384, 0, 1,1);
    launch_tconv16(stream, bufQh + 768, 1152, 2048ll*1152, 0, 1, 2048, 384, Vt, 2048, 384ll*2048, 4);
    launch_gemm16(stream, bufQh,1152,2048ll*1152, bufQh+384,1152,2048ll*1152,
                  nullptr, nullptr,0,0, Sb16,2048,2048ll*2048,1, 2048,2048,384, 0, 4,1);
    softmax_bf16<<<dim3(2048,4),256,0,stream>>>(Sb16,2048,2048ll*2048,2048,
                0.05103103630798288f, maskp, (long long)i*2048*2048, 2048, flag);
    hipMemsetAsync(bufO, 0, 8192ll*384*4, stream);
    launch_gemm16(stream, Sb16,2048,2048ll*2048, Vt,2048,384ll*2048,
                  nullptr, nullptr,0,0, bufO,384,2048ll*384,0, 2048,384,2048, 0, 4,2);
    launch_cvt(stream, bufO, bufOh, 8192ll*384);
    launch_gemm16(stream, bufOh,384,0, a1projT + (long long)i*384*384,384,0,
                  a1_proj_b + (long long)i*384, ptsb,384,0,
                  bufT,384,0,0, 8192,384,384, 0, 1,1);
    hipMemsetAsync(gc, 0, 4096*4, stream);
    hipMemsetAsync(gsum, 0, 4096ll*384*4, stream);
    hipMemsetAsync(gmaxe, 0, 4096ll*384*4, stream);
    scatter_seg_kernel<<<8192,128,0,stream>>>(bufT, fgi + (long long)i*8192, gsum, gmaxe, gc);
    cell_kernel<<<4096,128,0,stream>>>(gsum, gmaxe, gc,
        bn2_g + (long long)i*384, bn2_b + (long long)i*384,
        bn2_m + (long long)i*384, bn2_v + (long long)i*384,
        cell2 + (long long)i*4096*384);
  }

  // ---- phase 4: combine ----
  combine_kernel<<<8192,128,0,stream>>>(ptsb, cell3, cluster, cell2, fgi, out);
}